// Round 2
// baseline (125.054 us; speedup 1.0000x reference)
//
#include <hip/hip_runtime.h>

// pred_vol (1,1,64,512,512) fp32; thresh 0.5; 9x9x9 max-pool NMS.
// Identity: thr is monotone and the window contains the center, so
// reference output == (c > 0.5 && c == max999_raw(x)) ? c : 0.
//
// v3 (this round): shared vertical pass + single-barrier pipeline.
//  - Vertical 9-max computed ONCE per column by threads 0..127 (12 reads ->
//    4 window maxes via prefix/suffix sharing), not 4x redundantly (36 reads).
//  - Vertical(plane t) runs concurrently with horizontal+emit(plane t-1);
//    bcol double-buffered -> ONE barrier per d-step instead of two.
//  - LDS wave-ops/block-step: 120 -> 80 (DMA 24 + vread 24 + bw 8 + hread 24),
//    barriers 48 -> 25 per block. LDS-pipe busy ~29us -> ~20us (HBM floor ~21us).
static constexpr int Dd = 64;
static constexpr int Hh = 512;
static constexpr int Ww = 512;
static constexpr int RAD = 4;
static constexpr float THRESH_V = 0.5f;
static constexpr int W4 = Ww / 4;           // 128 float4 per row
static constexpr int PLANE4 = Hh * W4;      // 65536 float4 per D-plane

static constexpr int TH = 4;                // output h-rows per block
static constexpr int DC = 16;               // output d-planes per block
static constexpr int ROWS = TH + 2 * RAD;   // 12 staged raw rows per plane
static constexpr int NPL = DC + 2 * RAD;    // 24 planes touched per block
static constexpr int NBLK = (Hh / TH) * (Dd / DC);  // 512 blocks (2/CU)

typedef float nf4 __attribute__((ext_vector_type(4)));

__device__ __forceinline__ float4 f4max(float4 a, float4 b) {
    return make_float4(fmaxf(a.x, b.x), fmaxf(a.y, b.y), fmaxf(a.z, b.z), fmaxf(a.w, b.w));
}
__device__ __forceinline__ int iclamp(int v, int lo, int hi) {
    return v < lo ? lo : (v > hi ? hi : v);
}

// Counted-vmcnt barrier: wait own DMA writes (leaving N newer VMEM ops, i.e.
// this step's output store, in flight) + all LDS ops, then barrier.
#define BAR_VM(N) asm volatile("s_waitcnt vmcnt(" #N ") lgkmcnt(0)\n\ts_barrier" ::: "memory")
#define BAR_LDS() asm volatile("s_waitcnt lgkmcnt(0)\n\ts_barrier" ::: "memory")

// Direct global->LDS DMA, 16B per lane, dest = wave-uniform base + lane*16.
__device__ __forceinline__ void load_lds16(const float4* g, float4* l) {
    __builtin_amdgcn_global_load_lds(
        (const __attribute__((address_space(1))) void*)g,
        (__attribute__((address_space(3))) void*)l, 16, 0, 0);
}

// (512,2): min-blocks semantics -> 2 blocks/CU, 128-VGPR cap.
__global__ __launch_bounds__(512, 2)
void fused_nms_k(const float4* __restrict__ x4, float4* __restrict__ o4) {
    // raw rows double-buffered (48 KB) + col-max rows double-buffered (16 KB)
    __shared__ float4 braw[2][ROWS * W4];
    __shared__ float4 bcol[2][TH * W4];

    const int tid  = threadIdx.x;
    const int w4   = tid & (W4 - 1);   // 0..127
    const int hr   = tid >> 7;         // 0..3 (output row within block)
    const int wid  = tid >> 6;         // wave 0..7
    const int lane = tid & 63;

    // XCD swizzle: band = blockIdx&7 -> h-band of 64 rows stays on one XCD's L2
    const int b    = blockIdx.x;
    const int band = b & 7;
    const int rest = b >> 3;           // 0..63
    const int ht   = band * 16 + (rest & 15);  // 0..127
    const int dc   = rest >> 4;        // 0..3
    const int h0   = ht * TH;
    const int d0   = dc * DC;

    const int colm = w4 ? w4 - 1 : 0;
    const int colp = (w4 < W4 - 1) ? w4 + 1 : W4 - 1;
    const int outrow = (h0 + hr) * W4 + w4;

    // Staging descriptors: 24 segments (12 rows x 2 half-rows), 3 per wave.
    int goff[3], loff[3];
#pragma unroll
    for (int k = 0; k < 3; ++k) {
        const int s    = wid + 8 * k;          // 0..23
        const int row  = s >> 1;               // 0..11
        const int half = s & 1;                // 0/1
        const int gh   = iclamp(h0 - RAD + row, 0, Hh - 1);
        goff[k] = gh * W4 + half * 64 + lane;
        loff[k] = row * W4 + half * 64;
    }

    auto stage = [&](int p) {  // stage plane index p into braw[p&1]
        const int gd = iclamp(d0 - RAD + p, 0, Dd - 1);
        const float4* pl = x4 + (size_t)gd * PLANE4;
#pragma unroll
        for (int k = 0; k < 3; ++k)
            load_lds16(pl + goff[k], &braw[p & 1][loff[k]]);
    };

    // Vertical 9-max for plane p: threads 0..127 own one column each, read the
    // 12 staged rows once, produce all 4 window maxes via shared core.
    auto vert = [&](int p) {
        if (tid < W4) {
            const float4* B = &braw[p & 1][tid];
            float4 core = f4max(f4max(f4max(B[3 * W4], B[4 * W4]),
                                      f4max(B[5 * W4], B[6 * W4])),
                                f4max(B[7 * W4], B[8 * W4]));
            float4 q0 = B[0], q1 = B[1 * W4], q2 = B[2 * W4];
            float4 q9 = B[9 * W4], q10 = B[10 * W4], q11 = B[11 * W4];
            float4 b12 = f4max(q1, q2), c910 = f4max(q9, q10);
            float4* O = &bcol[p & 1][tid];
            O[0 * W4] = f4max(core, f4max(q0, b12));    // rows 0..8
            O[1 * W4] = f4max(core, f4max(b12, q9));    // rows 1..9
            O[2 * W4] = f4max(core, f4max(q2, c910));   // rows 2..10
            O[3 * W4] = f4max(core, f4max(c910, q11));  // rows 3..11
        }
    };

    // Slot ring: R[i&7] holds the HxW-maxed row of plane index i.
    float4 R[8];

    // 25 steps, fully unrolled so all flags/slots/parities are compile-time.
    // Step t: horizontal+emit for plane t-1 (reads bcol[(t-1)&1]),
    //         vertical for plane t (braw[t&1] -> bcol[t&1]),
    //         DMA plane t+1, one barrier.
#pragma unroll
    for (int t = 0; t <= NPL; ++t) {
        const bool doH   = (t >= 1);
        const bool doE   = (t >= 9);           // emit output plane j = t-9
        const bool doV   = (t <= NPL - 1);     // planes 0..23
        const bool doDMA = (t <= NPL - 2);     // stage planes 1..23

        // (1) center load first (pinned before DMA so its wait is counted),
        float4 cen;
        if (doE) {
            cen = x4[(size_t)(d0 + t - 9) * PLANE4 + outrow];
            __builtin_amdgcn_sched_barrier(0);
        }
        // (2) next-plane DMA — in flight across the whole step.
        if (doDMA) stage(t + 1);

        // (3) vertical pass for plane t (independent of horizontal below).
        if (doV) vert(t);

        // (4) horizontal 9-window + D-ring + emit for plane t-1.
        if (doH) {
            const float4* Bc = &bcol[(t - 1) & 1][hr * W4];
            const float4 lm = Bc[colm], cm = Bc[w4], rm = Bc[colp];
            const float l3 = lm.w, l2 = fmaxf(lm.z, l3), l1 = fmaxf(lm.y, l2), l0 = fmaxf(lm.x, l1);
            const float core = fmaxf(fmaxf(cm.x, cm.y), fmaxf(cm.z, cm.w));
            const float r0 = rm.x, r1 = fmaxf(r0, rm.y), r2 = fmaxf(r1, rm.z), r3 = fmaxf(r2, rm.w);
            float4 pm;
            pm.x = fmaxf(l0, fmaxf(core, r0));
            pm.y = fmaxf(l1, fmaxf(core, r1));
            pm.z = fmaxf(l2, fmaxf(core, r2));
            pm.w = fmaxf(l3, fmaxf(core, r3));

            if (doE) {
                float4 mm = pm;
#pragma unroll
                for (int i = 0; i < 8; ++i) mm = f4max(mm, R[i]);
                nf4 q;
                q.x = (cen.x > THRESH_V && cen.x == mm.x) ? cen.x : 0.0f;
                q.y = (cen.y > THRESH_V && cen.y == mm.y) ? cen.y : 0.0f;
                q.z = (cen.z > THRESH_V && cen.z == mm.z) ? cen.z : 0.0f;
                q.w = (cen.w > THRESH_V && cen.w == mm.w) ? cen.w : 0.0f;
                __builtin_nontemporal_store(
                    q, (nf4*)&o4[(size_t)(d0 + t - 9) * PLANE4 + outrow]);
            }
            R[(t - 1) & 7] = pm;  // overwrite after use
        }

        // (5) one barrier: publishes this step's bcol writes, gates next
        //     step's braw reads on our DMA. Counted vmcnt keeps the output
        //     store (the only newer VMEM op) in flight.
        if (t == 0) {
            BAR_VM(0);
        } else if (t <= 8) {
            BAR_VM(0);           // no stores outstanding yet
        } else if (doDMA) {
            BAR_VM(1);           // leave this step's store in flight
        } else if (t == NPL - 1) {
            BAR_LDS();           // t=23: no DMA to gate, publish bcol only
        }                        // t=24: last step, no barrier
    }
    // prologue plane 0 staged before the loop:
    // (placed after the loop textually is wrong — see launch wrapper below)
}

// NOTE: plane 0 must be staged before step 0's vertical pass. We do it via a
// tiny prologue kernel-side: the loop above expects braw[0] ready at t=0, so
// kernel entry stages it and barriers first.
__global__ __launch_bounds__(512, 2)
void fused_nms_entry(const float4* __restrict__ x4, float4* __restrict__ o4);

extern "C" void kernel_launch(void* const* d_in, const int* in_sizes, int n_in,
                              void* d_out, int out_size, void* d_ws, size_t ws_size,
                              hipStream_t stream);

// --- actual kernel with prologue staged correctly ---
__global__ __launch_bounds__(512, 2)
void fused_nms_k2(const float4* __restrict__ x4, float4* __restrict__ o4) {
    __shared__ float4 braw[2][ROWS * W4];
    __shared__ float4 bcol[2][TH * W4];

    const int tid  = threadIdx.x;
    const int w4   = tid & (W4 - 1);
    const int hr   = tid >> 7;
    const int wid  = tid >> 6;
    const int lane = tid & 63;

    const int b    = blockIdx.x;
    const int band = b & 7;
    const int rest = b >> 3;
    const int ht   = band * 16 + (rest & 15);
    const int dc   = rest >> 4;
    const int h0   = ht * TH;
    const int d0   = dc * DC;

    const int colm = w4 ? w4 - 1 : 0;
    const int colp = (w4 < W4 - 1) ? w4 + 1 : W4 - 1;
    const int outrow = (h0 + hr) * W4 + w4;

    int goff[3], loff[3];
#pragma unroll
    for (int k = 0; k < 3; ++k) {
        const int s    = wid + 8 * k;
        const int row  = s >> 1;
        const int half = s & 1;
        const int gh   = iclamp(h0 - RAD + row, 0, Hh - 1);
        goff[k] = gh * W4 + half * 64 + lane;
        loff[k] = row * W4 + half * 64;
    }

    auto stage = [&](int p) {
        const int gd = iclamp(d0 - RAD + p, 0, Dd - 1);
        const float4* pl = x4 + (size_t)gd * PLANE4;
#pragma unroll
        for (int k = 0; k < 3; ++k)
            load_lds16(pl + goff[k], &braw[p & 1][loff[k]]);
    };

    auto vert = [&](int p) {
        if (tid < W4) {
            const float4* B = &braw[p & 1][tid];
            float4 core = f4max(f4max(f4max(B[3 * W4], B[4 * W4]),
                                      f4max(B[5 * W4], B[6 * W4])),
                                f4max(B[7 * W4], B[8 * W4]));
            float4 q0 = B[0], q1 = B[1 * W4], q2 = B[2 * W4];
            float4 q9 = B[9 * W4], q10 = B[10 * W4], q11 = B[11 * W4];
            float4 b12 = f4max(q1, q2), c910 = f4max(q9, q10);
            float4* O = &bcol[p & 1][tid];
            O[0 * W4] = f4max(core, f4max(q0, b12));
            O[1 * W4] = f4max(core, f4max(b12, q9));
            O[2 * W4] = f4max(core, f4max(q2, c910));
            O[3 * W4] = f4max(core, f4max(c910, q11));
        }
    };

    float4 R[8];

    stage(0);
    BAR_VM(0);

#pragma unroll
    for (int t = 0; t <= NPL; ++t) {
        const bool doH   = (t >= 1);
        const bool doE   = (t >= 9);
        const bool doV   = (t <= NPL - 1);
        const bool doDMA = (t <= NPL - 2);

        float4 cen;
        if (doE) {
            cen = x4[(size_t)(d0 + t - 9) * PLANE4 + outrow];
            __builtin_amdgcn_sched_barrier(0);
        }
        if (doDMA) stage(t + 1);
        if (doV) vert(t);

        if (doH) {
            const float4* Bc = &bcol[(t - 1) & 1][hr * W4];
            const float4 lm = Bc[colm], cm = Bc[w4], rm = Bc[colp];
            const float l3 = lm.w, l2 = fmaxf(lm.z, l3), l1 = fmaxf(lm.y, l2), l0 = fmaxf(lm.x, l1);
            const float core = fmaxf(fmaxf(cm.x, cm.y), fmaxf(cm.z, cm.w));
            const float r0 = rm.x, r1 = fmaxf(r0, rm.y), r2 = fmaxf(r1, rm.z), r3 = fmaxf(r2, rm.w);
            float4 pm;
            pm.x = fmaxf(l0, fmaxf(core, r0));
            pm.y = fmaxf(l1, fmaxf(core, r1));
            pm.z = fmaxf(l2, fmaxf(core, r2));
            pm.w = fmaxf(l3, fmaxf(core, r3));

            if (doE) {
                float4 mm = pm;
#pragma unroll
                for (int i = 0; i < 8; ++i) mm = f4max(mm, R[i]);
                nf4 q;
                q.x = (cen.x > THRESH_V && cen.x == mm.x) ? cen.x : 0.0f;
                q.y = (cen.y > THRESH_V && cen.y == mm.y) ? cen.y : 0.0f;
                q.z = (cen.z > THRESH_V && cen.z == mm.z) ? cen.z : 0.0f;
                q.w = (cen.w > THRESH_V && cen.w == mm.w) ? cen.w : 0.0f;
                __builtin_nontemporal_store(
                    q, (nf4*)&o4[(size_t)(d0 + t - 9) * PLANE4 + outrow]);
            }
            R[(t - 1) & 7] = pm;
        }

        if (t <= 8) {
            BAR_VM(0);
        } else if (doDMA) {
            BAR_VM(1);
        } else if (t == NPL - 1) {
            BAR_LDS();
        }
    }
}

extern "C" void kernel_launch(void* const* d_in, const int* in_sizes, int n_in,
                              void* d_out, int out_size, void* d_ws, size_t ws_size,
                              hipStream_t stream) {
    const float4* x4 = (const float4*)d_in[0];
    float4* out4 = (float4*)d_out;
    (void)d_ws; (void)ws_size; (void)in_sizes; (void)n_in; (void)out_size;
    fused_nms_k2<<<dim3(NBLK), dim3(512), 0, stream>>>(x4, out4);
}